// Round 10
// baseline (246.273 us; speedup 1.0000x reference)
//
#include <hip/hip_runtime.h>

// SNN classifier: T=500, B=256, 96 -> 64 -> 80, leaky (subtract reset).
// f32 BLAS-order arithmetic replicated exactly (single-accumulator
// k-ascending __fmaf_rn chains; fixed leaky op-sequence) -> outputs
// bitwise-identical to the passing round-2..9 kernels.
//
// Round-10: round-9 (216us, VALUBusy 11%) died on lgkmcnt MIXING: SMEM
// (s_load W1) and DS (ds_read x) share lgkmcnt and SMEM completes
// out-of-order, so every ds-dependent FMA forced lgkmcnt(0), draining the
// scalar pipe serially. Fix: phase-separate the pipes. Per 48-k half:
//   sched_barrier(0) | 12x ds_read_b128 -> xr[48] regs | sched_barrier(0)
//   | pure {s_load W1 + FMA} unrolled loop (SMEM-only in flight).
// LDS staging stays (it killed the global gather: FETCH 86->24MB).
// Direct per-lane stores (non-blocking). One __syncthreads per kernel.
// K2/K4 untouched.

#define T_STEPS 500
#define BATCH   256
#define N_IN    96
#define N_HID   64
#define N_OUT   80
#define CH      50   // chunk size in K2/K4 (500 = 10*50)

#define XSTR    100  // K1 LDS row stride (dwords): 16B-aligned, mild 4-mod-32
#define SSTR    68   // K3 LDS row stride (dwords)

// ---------------- K1: cur1 = x @ W1 + b1 ----------------
// grid 500*4, block 256 (4 waves). Block = (t, 64-b group); wave = o-quarter.
__global__ __launch_bounds__(256) void k1_cur1(
    const float* __restrict__ x,   // (T,B,96)
    const float* __restrict__ W1,  // (96,64)
    const float* __restrict__ b1,  // (64)
    float* __restrict__ cur1)      // (T,B,64) region inside outs
{
    const int t    = blockIdx.x >> 2;
    const int bg   = blockIdx.x & 3;
    const int b0   = bg << 6;
    const int lane = threadIdx.x & 63;   // = local b
    const int w    = threadIdx.x >> 6;   // wave id = o-quarter
    const int o0   = w << 4;

    __shared__ float sm[64 * XSTR];      // 25.6 KB

    // ---- stage: 64x96 contiguous global region -> LDS (coalesced)
    {
        const float4* __restrict__ src =
            reinterpret_cast<const float4*>(x + ((size_t)t * BATCH + b0) * N_IN);
        for (int i = threadIdx.x; i < 1536; i += 256) {     // 6 iters
            const float4 v = src[i];
            const int row = i / 24, g = i % 24;
            *reinterpret_cast<float4*>(&sm[row * XSTR + g * 4]) = v;
        }
    }
    __syncthreads();

    float acc[16];
    #pragma unroll
    for (int o = 0; o < 16; ++o) acc[o] = 0.0f;

    #pragma unroll 1
    for (int kh = 0; kh < 2; ++kh) {     // two 48-k halves
        // ---- phase A: LDS -> registers (DS-only)
        __builtin_amdgcn_sched_barrier(0);
        float xr[48];
        #pragma unroll
        for (int q = 0; q < 12; ++q) {
            const float4 v = *reinterpret_cast<const float4*>(
                &sm[lane * XSTR + kh * 48 + q * 4]);
            xr[q * 4 + 0] = v.x; xr[q * 4 + 1] = v.y;
            xr[q * 4 + 2] = v.z; xr[q * 4 + 3] = v.w;
        }
        __builtin_amdgcn_sched_barrier(0);

        // ---- phase B: pure SMEM(W1) + FMA (no DS in flight)
        #pragma unroll
        for (int j = 0; j < 48; ++j) {
            const int k = kh * 48 + j;
            const float4* __restrict__ wr =
                reinterpret_cast<const float4*>(W1 + (size_t)k * N_HID + o0);
            const float4 w0 = wr[0], w1 = wr[1], w2 = wr[2], w3 = wr[3];
            const float xv = xr[j];
            acc[0]  = __fmaf_rn(xv, w0.x, acc[0]);
            acc[1]  = __fmaf_rn(xv, w0.y, acc[1]);
            acc[2]  = __fmaf_rn(xv, w0.z, acc[2]);
            acc[3]  = __fmaf_rn(xv, w0.w, acc[3]);
            acc[4]  = __fmaf_rn(xv, w1.x, acc[4]);
            acc[5]  = __fmaf_rn(xv, w1.y, acc[5]);
            acc[6]  = __fmaf_rn(xv, w1.z, acc[6]);
            acc[7]  = __fmaf_rn(xv, w1.w, acc[7]);
            acc[8]  = __fmaf_rn(xv, w2.x, acc[8]);
            acc[9]  = __fmaf_rn(xv, w2.y, acc[9]);
            acc[10] = __fmaf_rn(xv, w2.z, acc[10]);
            acc[11] = __fmaf_rn(xv, w2.w, acc[11]);
            acc[12] = __fmaf_rn(xv, w3.x, acc[12]);
            acc[13] = __fmaf_rn(xv, w3.y, acc[13]);
            acc[14] = __fmaf_rn(xv, w3.z, acc[14]);
            acc[15] = __fmaf_rn(xv, w3.w, acc[15]);
        }
    }

    // ---- bias + direct per-lane stores (non-blocking)
    float* dst = cur1 + ((size_t)t * BATCH + b0 + lane) * N_HID + o0;
    #pragma unroll
    for (int o4 = 0; o4 < 4; ++o4) {
        float4 v;
        v.x = __fadd_rn(acc[o4 * 4 + 0], b1[o0 + o4 * 4 + 0]);
        v.y = __fadd_rn(acc[o4 * 4 + 1], b1[o0 + o4 * 4 + 1]);
        v.z = __fadd_rn(acc[o4 * 4 + 2], b1[o0 + o4 * 4 + 2]);
        v.w = __fadd_rn(acc[o4 * 4 + 3], b1[o0 + o4 * 4 + 3]);
        reinterpret_cast<float4*>(dst)[o4] = v;
    }
}

// ---------------- K2: layer-1 recurrence (in-place cur1 -> spk) ----------------
__global__ __launch_bounds__(64) void k2_rec1(float* cs)  // outs region
{
    const int b = blockIdx.x;
    const int h = threadIdx.x;
    const size_t str  = (size_t)BATCH * N_HID;
    const size_t base = (size_t)b * N_HID + h;

    float A[CH], Bv[CH];
    #pragma unroll
    for (int i = 0; i < CH; ++i) A[i] = cs[(size_t)i * str + base];

    float mem = 0.f, s = 0.f;
    for (int cp = 0; cp < 5; ++cp) {            // 10 chunks, processed in pairs
        const int c0 = 2 * cp;
        #pragma unroll
        for (int i = 0; i < CH; ++i)            // prefetch chunk c0+1
            Bv[i] = cs[(size_t)((c0 + 1) * CH + i) * str + base];
        #pragma unroll
        for (int i = 0; i < CH; ++i) {          // compute chunk c0 from A
            const float m = __fsub_rn(__fadd_rn(__fmul_rn(0.95f, mem), A[i]), s);
            mem = m; s = (m > 1.0f) ? 1.0f : 0.0f;
            cs[(size_t)(c0 * CH + i) * str + base] = s;
        }
        if (cp < 4) {
            #pragma unroll
            for (int i = 0; i < CH; ++i)        // prefetch chunk c0+2
                A[i] = cs[(size_t)((c0 + 2) * CH + i) * str + base];
        }
        #pragma unroll
        for (int i = 0; i < CH; ++i) {          // compute chunk c0+1 from Bv
            const float m = __fsub_rn(__fadd_rn(__fmul_rn(0.95f, mem), Bv[i]), s);
            mem = m; s = (m > 1.0f) ? 1.0f : 0.0f;
            cs[(size_t)((c0 + 1) * CH + i) * str + base] = s;
        }
    }
}

// ---------------- K3: cur2 = spk @ W2 + b2 ----------------
// grid 500*4, block 256 (4 waves). Block = (t, 64-b group); wave = 20-o slice.
__global__ __launch_bounds__(256) void k3_cur2(
    const float* __restrict__ spk,  // (T,B,64) in outs
    const float* __restrict__ W2,   // (64,80)
    const float* __restrict__ b2,   // (80)
    float* __restrict__ cur2)       // (T,B,80) = outm region
{
    const int t    = blockIdx.x >> 2;
    const int bg   = blockIdx.x & 3;
    const int b0   = bg << 6;
    const int lane = threadIdx.x & 63;   // = local b
    const int w    = threadIdx.x >> 6;   // wave id
    const int o0   = w * 20;

    __shared__ float sm[64 * SSTR];      // 17.4 KB

    // ---- stage: 64x64 contiguous global region -> LDS (coalesced)
    {
        const float4* __restrict__ src =
            reinterpret_cast<const float4*>(spk + ((size_t)t * BATCH + b0) * N_HID);
        for (int i = threadIdx.x; i < 1024; i += 256) {     // 4 iters
            const float4 v = src[i];
            const int row = i / 16, g = i % 16;
            *reinterpret_cast<float4*>(&sm[row * SSTR + g * 4]) = v;
        }
    }
    __syncthreads();

    float acc[20];
    #pragma unroll
    for (int o = 0; o < 20; ++o) acc[o] = 0.0f;

    #pragma unroll 1
    for (int kh = 0; kh < 2; ++kh) {     // two 32-k halves
        __builtin_amdgcn_sched_barrier(0);
        float xr[32];
        #pragma unroll
        for (int q = 0; q < 8; ++q) {
            const float4 v = *reinterpret_cast<const float4*>(
                &sm[lane * SSTR + kh * 32 + q * 4]);
            xr[q * 4 + 0] = v.x; xr[q * 4 + 1] = v.y;
            xr[q * 4 + 2] = v.z; xr[q * 4 + 3] = v.w;
        }
        __builtin_amdgcn_sched_barrier(0);

        #pragma unroll
        for (int j = 0; j < 32; ++j) {
            const int k = kh * 32 + j;
            const float4* __restrict__ wr =
                reinterpret_cast<const float4*>(W2 + (size_t)k * N_OUT + o0);
            const float4 w0 = wr[0], w1 = wr[1], w2 = wr[2], w3 = wr[3], w4 = wr[4];
            const float sv = xr[j];
            acc[0]  = __fmaf_rn(sv, w0.x, acc[0]);
            acc[1]  = __fmaf_rn(sv, w0.y, acc[1]);
            acc[2]  = __fmaf_rn(sv, w0.z, acc[2]);
            acc[3]  = __fmaf_rn(sv, w0.w, acc[3]);
            acc[4]  = __fmaf_rn(sv, w1.x, acc[4]);
            acc[5]  = __fmaf_rn(sv, w1.y, acc[5]);
            acc[6]  = __fmaf_rn(sv, w1.z, acc[6]);
            acc[7]  = __fmaf_rn(sv, w1.w, acc[7]);
            acc[8]  = __fmaf_rn(sv, w2.x, acc[8]);
            acc[9]  = __fmaf_rn(sv, w2.y, acc[9]);
            acc[10] = __fmaf_rn(sv, w2.z, acc[10]);
            acc[11] = __fmaf_rn(sv, w2.w, acc[11]);
            acc[12] = __fmaf_rn(sv, w3.x, acc[12]);
            acc[13] = __fmaf_rn(sv, w3.y, acc[13]);
            acc[14] = __fmaf_rn(sv, w3.z, acc[14]);
            acc[15] = __fmaf_rn(sv, w3.w, acc[15]);
            acc[16] = __fmaf_rn(sv, w4.x, acc[16]);
            acc[17] = __fmaf_rn(sv, w4.y, acc[17]);
            acc[18] = __fmaf_rn(sv, w4.z, acc[18]);
            acc[19] = __fmaf_rn(sv, w4.w, acc[19]);
        }
    }

    float* dst = cur2 + ((size_t)t * BATCH + b0 + lane) * N_OUT + o0;
    #pragma unroll
    for (int o4 = 0; o4 < 5; ++o4) {
        float4 v;
        v.x = __fadd_rn(acc[o4 * 4 + 0], b2[o0 + o4 * 4 + 0]);
        v.y = __fadd_rn(acc[o4 * 4 + 1], b2[o0 + o4 * 4 + 1]);
        v.z = __fadd_rn(acc[o4 * 4 + 2], b2[o0 + o4 * 4 + 2]);
        v.w = __fadd_rn(acc[o4 * 4 + 3], b2[o0 + o4 * 4 + 3]);
        reinterpret_cast<float4*>(dst)[o4] = v;
    }
}

// ---------------- K4: layer-2 recurrence (cur2 in outm -> spk/mem finals) ----------------
__global__ __launch_bounds__(80) void k4_rec2(float* cm, float* os)
{
    const int b = blockIdx.x;
    const int o = threadIdx.x;   // 0..79
    const size_t str  = (size_t)BATCH * N_OUT;
    const size_t base = (size_t)b * N_OUT + o;

    float A[CH], Bv[CH];
    #pragma unroll
    for (int i = 0; i < CH; ++i) A[i] = cm[(size_t)i * str + base];

    float mem = 0.f, s = 0.f;
    for (int cp = 0; cp < 5; ++cp) {
        const int c0 = 2 * cp;
        #pragma unroll
        for (int i = 0; i < CH; ++i)
            Bv[i] = cm[(size_t)((c0 + 1) * CH + i) * str + base];
        #pragma unroll
        for (int i = 0; i < CH; ++i) {
            const int t = c0 * CH + i;
            const float m = __fsub_rn(__fadd_rn(__fmul_rn(0.95f, mem), A[i]), s);
            mem = m; s = (m > 1.0f) ? 1.0f : 0.0f;
            os[(size_t)t * str + base] = s;
            cm[(size_t)t * str + base] = m;
        }
        if (cp < 4) {
            #pragma unroll
            for (int i = 0; i < CH; ++i)
                A[i] = cm[(size_t)((c0 + 2) * CH + i) * str + base];
        }
        #pragma unroll
        for (int i = 0; i < CH; ++i) {
            const int t = (c0 + 1) * CH + i;
            const float m = __fsub_rn(__fadd_rn(__fmul_rn(0.95f, mem), Bv[i]), s);
            mem = m; s = (m > 1.0f) ? 1.0f : 0.0f;
            os[(size_t)t * str + base] = s;
            cm[(size_t)t * str + base] = m;
        }
    }
}

extern "C" void kernel_launch(void* const* d_in, const int* in_sizes, int n_in,
                              void* d_out, int out_size, void* d_ws, size_t ws_size,
                              hipStream_t stream) {
    const float* x  = (const float*)d_in[0];
    const float* W1 = (const float*)d_in[1];
    const float* b1 = (const float*)d_in[2];
    const float* W2 = (const float*)d_in[3];
    const float* b2 = (const float*)d_in[4];
    float* outs = (float*)d_out;                                   // (T,B,80) spikes
    float* outm = outs + (size_t)T_STEPS * BATCH * N_OUT;          // (T,B,80) mem

    k1_cur1<<<T_STEPS * 4, 256, 0, stream>>>(x, W1, b1, outs);     // cur1 -> outs
    k2_rec1<<<BATCH, 64, 0, stream>>>(outs);                       // spk overwrites cur1
    k3_cur2<<<T_STEPS * 4, 256, 0, stream>>>(outs, W2, b2, outm);  // cur2 -> outm
    k4_rec2<<<BATCH, 80, 0, stream>>>(outm, outs);                 // finals in place
}

// Round 11
// 102.762 us; speedup vs baseline: 2.3965x; 2.3965x over previous
//
#include <hip/hip_runtime.h>

// SNN classifier: T=500, B=256, 96 -> 64 -> 80, leaky (subtract reset).
// f32 BLAS-order arithmetic replicated exactly (single-accumulator
// k-ascending __fmaf_rn chains; fixed leaky op-sequence) -> outputs
// bitwise-identical to the passing round-2..10 kernels.
//
// Round-11: rounds 6-10 proved the scalar(SMEM) path cannot stream weights
// (K$ thrash + SGPR-capped MLP + lgkmcnt mixing with DS; compiler auto-
// scalarizes any provably-uniform load of const __restrict data). Fix:
// DS-ONLY inner loops. Both operands staged in LDS:
//   - per-lane x/spk rows, stride 100/68 dwords (== 4 mod 32: 8 lanes/phase,
//     conflict-free optimal for ds_read_b128),
//   - W slices read as wave-uniform LDS BROADCASTS (same-address b128,
//     conflict-free, ~1-2cyc; LDS has no scalar port so it CANNOT be
//     turned into s_load).
// DS ops complete in-order -> incremental lgkmcnt pipelining works.
// Static LDS <= 64KB: K1 single-t (50.2KB, 3 blocks/CU), K3 t-pair
// (55.3KB, 2 blocks/CU). Outputs transpose through LDS -> linear stores.
// K2/K4 untouched.

#define T_STEPS 500
#define BATCH   256
#define N_IN    96
#define N_HID   64
#define N_OUT   80
#define CH      50    // chunk size in K2/K4 (500 = 10*50)

#define XSTR    100   // K1 x row stride (dwords), 4 mod 32
#define OSTR1   68    // K1 out row stride
#define SSTR    68    // K3 spk row stride, 4 mod 32
#define OSTR2   84    // K3 out row stride (20 mod 32, also conflict-free)

// ---------------- K1: cur1 = x @ W1 + b1 ----------------
// grid 500*4, block 256 (4 waves = 4 o-quarters). Block = (t, 64-b group).
// LDS: x [64][100] @0 (6400 dw) + W1 [96][64] @6400 (6144 dw) = 50.2 KB.
__global__ __launch_bounds__(256) void k1_cur1(
    const float* __restrict__ x,   // (T,B,96)
    const float* __restrict__ W1,  // (96,64)
    const float* __restrict__ b1,  // (64)
    float* __restrict__ cur1)      // (T,B,64) region inside outs
{
    const int t    = blockIdx.x >> 2;
    const int b0   = (blockIdx.x & 3) << 6;
    const int lane = threadIdx.x & 63;   // = local b
    const int w    = threadIdx.x >> 6;   // wave id = o-quarter
    const int o0   = w << 4;

    __shared__ float sm[12544];          // 50.2 KB

    // ---- stage x tile (coalesced) + full W1 (coalesced, linear)
    {
        const float4* __restrict__ src =
            reinterpret_cast<const float4*>(x + ((size_t)t * BATCH + b0) * N_IN);
        #pragma unroll
        for (int ii = 0; ii < 6; ++ii) {
            const int i = ii * 256 + threadIdx.x;
            const float4 v = src[i];
            const int row = i / 24, g = i % 24;
            *reinterpret_cast<float4*>(&sm[row * XSTR + g * 4]) = v;
        }
        const float4* __restrict__ srcw = reinterpret_cast<const float4*>(W1);
        #pragma unroll
        for (int ii = 0; ii < 6; ++ii) {
            const int i = ii * 256 + threadIdx.x;
            *reinterpret_cast<float4*>(&sm[6400 + i * 4]) = srcw[i];
        }
    }
    __syncthreads();

    float acc[16];
    #pragma unroll
    for (int o = 0; o < 16; ++o) acc[o] = 0.0f;

    const int xb = lane * XSTR;
    #pragma unroll 2
    for (int kg = 0; kg < 24; ++kg) {
        const float4 xv = *reinterpret_cast<const float4*>(&sm[xb + kg * 4]);
        const float xq[4] = {xv.x, xv.y, xv.z, xv.w};
        #pragma unroll
        for (int jj = 0; jj < 4; ++jj) {
            const int k = kg * 4 + jj;
            const float4* __restrict__ wr =                 // LDS broadcast
                reinterpret_cast<const float4*>(&sm[6400 + k * 64 + o0]);
            const float4 w0 = wr[0], w1 = wr[1], w2 = wr[2], w3 = wr[3];
            const float xs = xq[jj];
            acc[0]  = __fmaf_rn(xs, w0.x, acc[0]);
            acc[1]  = __fmaf_rn(xs, w0.y, acc[1]);
            acc[2]  = __fmaf_rn(xs, w0.z, acc[2]);
            acc[3]  = __fmaf_rn(xs, w0.w, acc[3]);
            acc[4]  = __fmaf_rn(xs, w1.x, acc[4]);
            acc[5]  = __fmaf_rn(xs, w1.y, acc[5]);
            acc[6]  = __fmaf_rn(xs, w1.z, acc[6]);
            acc[7]  = __fmaf_rn(xs, w1.w, acc[7]);
            acc[8]  = __fmaf_rn(xs, w2.x, acc[8]);
            acc[9]  = __fmaf_rn(xs, w2.y, acc[9]);
            acc[10] = __fmaf_rn(xs, w2.z, acc[10]);
            acc[11] = __fmaf_rn(xs, w2.w, acc[11]);
            acc[12] = __fmaf_rn(xs, w3.x, acc[12]);
            acc[13] = __fmaf_rn(xs, w3.y, acc[13]);
            acc[14] = __fmaf_rn(xs, w3.z, acc[14]);
            acc[15] = __fmaf_rn(xs, w3.w, acc[15]);
        }
    }

    // ---- bias, transpose via LDS (reuse x area), linear block store
    __syncthreads();                     // all x/W reads done
    #pragma unroll
    for (int o4 = 0; o4 < 4; ++o4) {
        float4 v;
        v.x = __fadd_rn(acc[o4 * 4 + 0], b1[o0 + o4 * 4 + 0]);
        v.y = __fadd_rn(acc[o4 * 4 + 1], b1[o0 + o4 * 4 + 1]);
        v.z = __fadd_rn(acc[o4 * 4 + 2], b1[o0 + o4 * 4 + 2]);
        v.w = __fadd_rn(acc[o4 * 4 + 3], b1[o0 + o4 * 4 + 3]);
        *reinterpret_cast<float4*>(&sm[lane * OSTR1 + o0 + o4 * 4]) = v;
    }
    __syncthreads();
    {
        float4* __restrict__ dst =
            reinterpret_cast<float4*>(cur1 + ((size_t)t * BATCH + b0) * N_HID);
        #pragma unroll
        for (int ii = 0; ii < 4; ++ii) {
            const int i = ii * 256 + threadIdx.x;
            const int row = i / 16, g = i % 16;
            dst[i] = *reinterpret_cast<const float4*>(&sm[row * OSTR1 + g * 4]);
        }
    }
}

// ---------------- K2: layer-1 recurrence (in-place cur1 -> spk) ----------------
__global__ __launch_bounds__(64) void k2_rec1(float* cs)  // outs region
{
    const int b = blockIdx.x;
    const int h = threadIdx.x;
    const size_t str  = (size_t)BATCH * N_HID;
    const size_t base = (size_t)b * N_HID + h;

    float A[CH], Bv[CH];
    #pragma unroll
    for (int i = 0; i < CH; ++i) A[i] = cs[(size_t)i * str + base];

    float mem = 0.f, s = 0.f;
    for (int cp = 0; cp < 5; ++cp) {            // 10 chunks, processed in pairs
        const int c0 = 2 * cp;
        #pragma unroll
        for (int i = 0; i < CH; ++i)            // prefetch chunk c0+1
            Bv[i] = cs[(size_t)((c0 + 1) * CH + i) * str + base];
        #pragma unroll
        for (int i = 0; i < CH; ++i) {          // compute chunk c0 from A
            const float m = __fsub_rn(__fadd_rn(__fmul_rn(0.95f, mem), A[i]), s);
            mem = m; s = (m > 1.0f) ? 1.0f : 0.0f;
            cs[(size_t)(c0 * CH + i) * str + base] = s;
        }
        if (cp < 4) {
            #pragma unroll
            for (int i = 0; i < CH; ++i)        // prefetch chunk c0+2
                A[i] = cs[(size_t)((c0 + 2) * CH + i) * str + base];
        }
        #pragma unroll
        for (int i = 0; i < CH; ++i) {          // compute chunk c0+1 from Bv
            const float m = __fsub_rn(__fadd_rn(__fmul_rn(0.95f, mem), Bv[i]), s);
            mem = m; s = (m > 1.0f) ? 1.0f : 0.0f;
            cs[(size_t)((c0 + 1) * CH + i) * str + base] = s;
        }
    }
}

// ---------------- K3: cur2 = spk @ W2 + b2 ----------------
// grid 250*4, block 256 (4 waves = 4 20-o slices). Block = (t-pair, 64-b).
// LDS: spk 2x[64][68] @0 (8704 dw) + W2 [64][80] @8704 (5120 dw) = 55.3 KB.
// Out reuses [0..10751] (overlaps W2 region; barrier-protected).
__global__ __launch_bounds__(256) void k3_cur2(
    const float* __restrict__ spk,  // (T,B,64) in outs
    const float* __restrict__ W2,   // (64,80)
    const float* __restrict__ b2,   // (80)
    float* __restrict__ cur2)       // (T,B,80) = outm region
{
    const int tp   = blockIdx.x >> 2;
    const int b0   = (blockIdx.x & 3) << 6;
    const int t0   = tp * 2;
    const int lane = threadIdx.x & 63;   // = local b
    const int w    = threadIdx.x >> 6;   // wave id
    const int o0   = w * 20;

    __shared__ float sm[13824];          // 55.3 KB

    // ---- stage spk tiles (coalesced) + full W2 (coalesced, linear)
    {
        const float4* __restrict__ s0 =
            reinterpret_cast<const float4*>(spk + ((size_t)t0 * BATCH + b0) * N_HID);
        const float4* __restrict__ s1 =
            reinterpret_cast<const float4*>(spk + ((size_t)(t0 + 1) * BATCH + b0) * N_HID);
        #pragma unroll
        for (int ii = 0; ii < 4; ++ii) {
            const int i = ii * 256 + threadIdx.x;
            const float4 v0 = s0[i], v1 = s1[i];
            const int row = i / 16, g = i % 16;
            *reinterpret_cast<float4*>(&sm[row * SSTR + g * 4]) = v0;
            *reinterpret_cast<float4*>(&sm[4352 + row * SSTR + g * 4]) = v1;
        }
        const float4* __restrict__ srcw = reinterpret_cast<const float4*>(W2);
        for (int i = threadIdx.x; i < 1280; i += 256)
            *reinterpret_cast<float4*>(&sm[8704 + i * 4]) = srcw[i];
    }
    __syncthreads();

    float acc0[20], acc1[20];
    #pragma unroll
    for (int o = 0; o < 20; ++o) { acc0[o] = 0.0f; acc1[o] = 0.0f; }

    const int xb0 = lane * SSTR;
    const int xb1 = 4352 + lane * SSTR;
    #pragma unroll 2
    for (int kg = 0; kg < 16; ++kg) {
        const float4 xv0 = *reinterpret_cast<const float4*>(&sm[xb0 + kg * 4]);
        const float4 xv1 = *reinterpret_cast<const float4*>(&sm[xb1 + kg * 4]);
        const float xq0[4] = {xv0.x, xv0.y, xv0.z, xv0.w};
        const float xq1[4] = {xv1.x, xv1.y, xv1.z, xv1.w};
        #pragma unroll
        for (int jj = 0; jj < 4; ++jj) {
            const int k = kg * 4 + jj;
            const float4* __restrict__ wr =                 // LDS broadcast
                reinterpret_cast<const float4*>(&sm[8704 + k * 80 + o0]);
            const float4 w0 = wr[0], w1 = wr[1], w2 = wr[2], w3 = wr[3], w4 = wr[4];
            const float a = xq0[jj], b = xq1[jj];
            acc0[0]  = __fmaf_rn(a, w0.x, acc0[0]);
            acc0[1]  = __fmaf_rn(a, w0.y, acc0[1]);
            acc0[2]  = __fmaf_rn(a, w0.z, acc0[2]);
            acc0[3]  = __fmaf_rn(a, w0.w, acc0[3]);
            acc0[4]  = __fmaf_rn(a, w1.x, acc0[4]);
            acc0[5]  = __fmaf_rn(a, w1.y, acc0[5]);
            acc0[6]  = __fmaf_rn(a, w1.z, acc0[6]);
            acc0[7]  = __fmaf_rn(a, w1.w, acc0[7]);
            acc0[8]  = __fmaf_rn(a, w2.x, acc0[8]);
            acc0[9]  = __fmaf_rn(a, w2.y, acc0[9]);
            acc0[10] = __fmaf_rn(a, w2.z, acc0[10]);
            acc0[11] = __fmaf_rn(a, w2.w, acc0[11]);
            acc0[12] = __fmaf_rn(a, w3.x, acc0[12]);
            acc0[13] = __fmaf_rn(a, w3.y, acc0[13]);
            acc0[14] = __fmaf_rn(a, w3.z, acc0[14]);
            acc0[15] = __fmaf_rn(a, w3.w, acc0[15]);
            acc0[16] = __fmaf_rn(a, w4.x, acc0[16]);
            acc0[17] = __fmaf_rn(a, w4.y, acc0[17]);
            acc0[18] = __fmaf_rn(a, w4.z, acc0[18]);
            acc0[19] = __fmaf_rn(a, w4.w, acc0[19]);
            acc1[0]  = __fmaf_rn(b, w0.x, acc1[0]);
            acc1[1]  = __fmaf_rn(b, w0.y, acc1[1]);
            acc1[2]  = __fmaf_rn(b, w0.z, acc1[2]);
            acc1[3]  = __fmaf_rn(b, w0.w, acc1[3]);
            acc1[4]  = __fmaf_rn(b, w1.x, acc1[4]);
            acc1[5]  = __fmaf_rn(b, w1.y, acc1[5]);
            acc1[6]  = __fmaf_rn(b, w1.z, acc1[6]);
            acc1[7]  = __fmaf_rn(b, w1.w, acc1[7]);
            acc1[8]  = __fmaf_rn(b, w2.x, acc1[8]);
            acc1[9]  = __fmaf_rn(b, w2.y, acc1[9]);
            acc1[10] = __fmaf_rn(b, w2.z, acc1[10]);
            acc1[11] = __fmaf_rn(b, w2.w, acc1[11]);
            acc1[12] = __fmaf_rn(b, w3.x, acc1[12]);
            acc1[13] = __fmaf_rn(b, w3.y, acc1[13]);
            acc1[14] = __fmaf_rn(b, w3.z, acc1[14]);
            acc1[15] = __fmaf_rn(b, w3.w, acc1[15]);
            acc1[16] = __fmaf_rn(b, w4.x, acc1[16]);
            acc1[17] = __fmaf_rn(b, w4.y, acc1[17]);
            acc1[18] = __fmaf_rn(b, w4.z, acc1[18]);
            acc1[19] = __fmaf_rn(b, w4.w, acc1[19]);
        }
    }

    // ---- bias, transpose via LDS, linear block stores
    __syncthreads();                     // all spk/W reads done
    #pragma unroll
    for (int o4 = 0; o4 < 5; ++o4) {
        float4 v0, v1;
        v0.x = __fadd_rn(acc0[o4 * 4 + 0], b2[o0 + o4 * 4 + 0]);
        v0.y = __fadd_rn(acc0[o4 * 4 + 1], b2[o0 + o4 * 4 + 1]);
        v0.z = __fadd_rn(acc0[o4 * 4 + 2], b2[o0 + o4 * 4 + 2]);
        v0.w = __fadd_rn(acc0[o4 * 4 + 3], b2[o0 + o4 * 4 + 3]);
        v1.x = __fadd_rn(acc1[o4 * 4 + 0], b2[o0 + o4 * 4 + 0]);
        v1.y = __fadd_rn(acc1[o4 * 4 + 1], b2[o0 + o4 * 4 + 1]);
        v1.z = __fadd_rn(acc1[o4 * 4 + 2], b2[o0 + o4 * 4 + 2]);
        v1.w = __fadd_rn(acc1[o4 * 4 + 3], b2[o0 + o4 * 4 + 3]);
        *reinterpret_cast<float4*>(&sm[lane * OSTR2 + o0 + o4 * 4]) = v0;
        *reinterpret_cast<float4*>(&sm[5376 + lane * OSTR2 + o0 + o4 * 4]) = v1;
    }
    __syncthreads();
    {
        float4* __restrict__ d0 =
            reinterpret_cast<float4*>(cur2 + ((size_t)t0 * BATCH + b0) * N_OUT);
        float4* __restrict__ d1 =
            reinterpret_cast<float4*>(cur2 + ((size_t)(t0 + 1) * BATCH + b0) * N_OUT);
        #pragma unroll
        for (int ii = 0; ii < 5; ++ii) {
            const int i = ii * 256 + threadIdx.x;
            const int row = i / 20, g = i % 20;
            d0[i] = *reinterpret_cast<const float4*>(&sm[row * OSTR2 + g * 4]);
            d1[i] = *reinterpret_cast<const float4*>(&sm[5376 + row * OSTR2 + g * 4]);
        }
    }
}

// ---------------- K4: layer-2 recurrence (cur2 in outm -> spk/mem finals) ----------------
__global__ __launch_bounds__(80) void k4_rec2(float* cm, float* os)
{
    const int b = blockIdx.x;
    const int o = threadIdx.x;   // 0..79
    const size_t str  = (size_t)BATCH * N_OUT;
    const size_t base = (size_t)b * N_OUT + o;

    float A[CH], Bv[CH];
    #pragma unroll
    for (int i = 0; i < CH; ++i) A[i] = cm[(size_t)i * str + base];

    float mem = 0.f, s = 0.f;
    for (int cp = 0; cp < 5; ++cp) {
        const int c0 = 2 * cp;
        #pragma unroll
        for (int i = 0; i < CH; ++i)
            Bv[i] = cm[(size_t)((c0 + 1) * CH + i) * str + base];
        #pragma unroll
        for (int i = 0; i < CH; ++i) {
            const int t = c0 * CH + i;
            const float m = __fsub_rn(__fadd_rn(__fmul_rn(0.95f, mem), A[i]), s);
            mem = m; s = (m > 1.0f) ? 1.0f : 0.0f;
            os[(size_t)t * str + base] = s;
            cm[(size_t)t * str + base] = m;
        }
        if (cp < 4) {
            #pragma unroll
            for (int i = 0; i < CH; ++i)
                A[i] = cm[(size_t)((c0 + 2) * CH + i) * str + base];
        }
        #pragma unroll
        for (int i = 0; i < CH; ++i) {
            const int t = (c0 + 1) * CH + i;
            const float m = __fsub_rn(__fadd_rn(__fmul_rn(0.95f, mem), Bv[i]), s);
            mem = m; s = (m > 1.0f) ? 1.0f : 0.0f;
            os[(size_t)t * str + base] = s;
            cm[(size_t)t * str + base] = m;
        }
    }
}

extern "C" void kernel_launch(void* const* d_in, const int* in_sizes, int n_in,
                              void* d_out, int out_size, void* d_ws, size_t ws_size,
                              hipStream_t stream) {
    const float* x  = (const float*)d_in[0];
    const float* W1 = (const float*)d_in[1];
    const float* b1 = (const float*)d_in[2];
    const float* W2 = (const float*)d_in[3];
    const float* b2 = (const float*)d_in[4];
    float* outs = (float*)d_out;                                   // (T,B,80) spikes
    float* outm = outs + (size_t)T_STEPS * BATCH * N_OUT;          // (T,B,80) mem

    k1_cur1<<<T_STEPS * 4, 256, 0, stream>>>(x, W1, b1, outs);     // cur1 -> outs
    k2_rec1<<<BATCH, 64, 0, stream>>>(outs);                       // spk overwrites cur1
    k3_cur2<<<250 * 4, 256, 0, stream>>>(outs, W2, b2, outm);      // cur2 -> outm
    k4_rec2<<<BATCH, 80, 0, stream>>>(outm, outs);                 // finals in place
}